// Round 8
// baseline (338.545 us; speedup 1.0000x reference)
//
#include <hip/hip_runtime.h>
#include <hip/hip_bf16.h>
#include <math.h>

// ALALLaDA router blend, factored + row-compacted form:
//   prep: scan + router softmax + bf16 compact pack + W1/W2 transpose-pack
//   Act_c[i, kf] = gelu(h_unm[i,:]·W1 + b1)               (GEMM1, M=Nu)
//   G_c[i, kf]   = w[a]*slidingwin(Act_c)                 (window kernel)
//   num_c[i,:]   = G_c[i,:]·W2s  (split-K=2 partials)     (GEMM2, M=Nm)
//   out = h + 0.08*LN((p0+p1+cnt*w·b2)/cnt) at active masked positions.
// GEMM: 64x128 tile, BK=32, 4 waves (2Mx2N), 3-buffer counted vmcnt(3)
// (T3/T4), 36KB LDS -> 4 blocks/CU, 1024 active blocks both GEMMs
// (co-residency is the measured binder: per-block-slot staging rate is
// ~constant, so time ~ staged_bytes / slots). Linear LDS (no swizzle:
// BK=32 row stride 64B defeats XOR spread; conflicts measured 2nd-order).

#define ALPHA 0.08f
#define EPS 1e-5f

typedef __attribute__((ext_vector_type(8))) __bf16 bf16x8;
typedef __attribute__((ext_vector_type(8))) short short8;
typedef __attribute__((ext_vector_type(4))) float f32x4;

__device__ __forceinline__ unsigned short f2bf(float f) {
  unsigned u = __float_as_uint(f);
  u += 0x7fffu + ((u >> 16) & 1u);
  return (unsigned short)(u >> 16);
}
__device__ __forceinline__ float bf2f(unsigned short b) {
  return __uint_as_float(((unsigned)b) << 16);
}

#define GLD16(gptr, lptr)                                                     \
  __builtin_amdgcn_global_load_lds(                                           \
      (const __attribute__((address_space(1))) void*)(gptr),                  \
      (__attribute__((address_space(3))) void*)(lptr), 16, 0, 0)

#define LD8(p) __builtin_bit_cast(bf16x8, *(const short8*)(p))

__device__ __forceinline__ int wave_incl_scan(int v, int lane) {
#pragma unroll
  for (int off = 1; off < 64; off <<= 1) {
    int t = __shfl_up(v, off);
    if (lane >= off) v += t;
  }
  return v;
}

// ---------------- prep: tpack (blocks 0..16383) + packrouter (16384..20479)
//                  + scan (block 20480), 256 threads each ----------------
__global__ __launch_bounds__(256) void prep_kernel(
    const float* __restrict__ h, const int* __restrict__ mask,
    const float* __restrict__ Wr, const float* __restrict__ br,
    const float* __restrict__ W1, const float* __restrict__ W2,
    const int* __restrict__ rptr, float* __restrict__ w,
    unsigned short* __restrict__ hbc, unsigned short* __restrict__ B1t,
    unsigned short* __restrict__ B2t, int* __restrict__ ru,
    int* __restrict__ msk_idx, int* __restrict__ pos2row,
    int* __restrict__ counts) {
  const int bid = blockIdx.x;
  const int tid = threadIdx.x;
  const int lane = tid & 63, wv = tid >> 6;

  if (bid < 16384) {  // ---- transpose-pack W1 / W2 ----
    __shared__ float tile[32][33];
    int id = bid;
    const float* src;
    unsigned short* dst;
    int C, c0, r0;
    size_t dstStride;
    if (id < 8192) {  // W1 [k][2048][512] -> B1t[(k*512+f)*2048 + d]
      const int k = id >> 10, rem = id & 1023;
      src = W1 + (size_t)k * 2048 * 512;
      dst = B1t + (size_t)k * 512 * 2048;
      C = 512; dstStride = 2048;
      c0 = (rem >> 6) * 32; r0 = (rem & 63) * 32;
    } else {          // W2 [k][512][2048] -> B2t[d*4096 + k*512 + f]
      id -= 8192;
      const int k = id >> 10, rem = id & 1023;
      src = W2 + (size_t)k * 512 * 2048;
      dst = B2t + (size_t)k * 512;
      C = 2048; dstStride = 4096;
      c0 = (rem >> 4) * 32; r0 = (rem & 15) * 32;
    }
    const int tx = tid & 31, ty = tid >> 5;
#pragma unroll
    for (int i = 0; i < 4; ++i)
      tile[ty + 8 * i][tx] = src[(size_t)(r0 + ty + 8 * i) * C + (c0 + tx)];
    __syncthreads();
#pragma unroll
    for (int i = 0; i < 4; ++i) {
      const int c = c0 + ty + 8 * i;
      dst[(size_t)c * dstStride + (size_t)(r0 + tx)] =
          f2bf(tile[tx][ty + 8 * i]);
    }
    return;
  }

  if (bid < 20480) {  // ---- router softmax + compact bf16 pack of h ----
    const int a = bid - 16384;
    const size_t base = (size_t)a * 2048;
    const int d0 = tid * 8;
    float hv[8];
    *(float4*)(hv) = *(const float4*)(h + base + d0);
    *(float4*)(hv + 4) = *(const float4*)(h + base + d0 + 4);
    float acc[8];
#pragma unroll
    for (int k = 0; k < 8; ++k) {
      float wvv[8];
      *(float4*)(wvv) = *(const float4*)(Wr + (size_t)k * 2048 + d0);
      *(float4*)(wvv + 4) = *(const float4*)(Wr + (size_t)k * 2048 + d0 + 4);
      float s = 0.f;
#pragma unroll
      for (int j = 0; j < 8; ++j) s += hv[j] * wvv[j];
      acc[k] = s;
    }
    // my compact row index: zeros in mask[0..a)  (self-computed, no dep)
    int c0n = 0;
    {
      const int4* m4p = (const int4*)mask;
#pragma unroll
      for (int q = 0; q < 4; ++q) {
        const int4 v = m4p[tid * 4 + q];
        const int b0 = tid * 16 + q * 4;
        c0n += (v.x == 0 && b0 + 0 < a);
        c0n += (v.y == 0 && b0 + 1 < a);
        c0n += (v.z == 0 && b0 + 2 < a);
        c0n += (v.w == 0 && b0 + 3 < a);
      }
    }
#pragma unroll
    for (int off = 32; off > 0; off >>= 1) {
      c0n += __shfl_down(c0n, off);
#pragma unroll
      for (int k = 0; k < 8; ++k) acc[k] += __shfl_down(acc[k], off);
    }
    __shared__ float red[4][8];
    __shared__ float logits[8];
    __shared__ int rucnt[4];
    __shared__ int rubc;
    if (lane == 0) {
#pragma unroll
      for (int k = 0; k < 8; ++k) red[wv][k] = acc[k];
      rucnt[wv] = c0n;
    }
    __syncthreads();
    if (tid < 8)
      logits[tid] =
          red[0][tid] + red[1][tid] + red[2][tid] + red[3][tid] + br[tid];
    if (tid == 0) rubc = rucnt[0] + rucnt[1] + rucnt[2] + rucnt[3];
    __syncthreads();
    if (tid == 0) {
      float mx = logits[0];
#pragma unroll
      for (int k = 1; k < 8; ++k) mx = fmaxf(mx, logits[k]);
      float e[8], se = 0.f;
#pragma unroll
      for (int k = 0; k < 8; ++k) {
        e[k] = expf(logits[k] - mx);
        se += e[k];
      }
      const float is = 1.f / se;
#pragma unroll
      for (int k = 0; k < 8; ++k) w[(size_t)a * 8 + k] = e[k] * is;
    }
    if (mask[a] == 0) {
      const int i = rubc;
      short8 o;
#pragma unroll
      for (int j = 0; j < 8; ++j) o[j] = (short)f2bf(hv[j]);
      *(short8*)(hbc + (size_t)i * 2048 + d0) = o;
    }
    return;
  }

  // ---- scan block (bid == 20480): ru, msk_idx, pos2row, counts ----
  {
    __shared__ int sru[4097];
    __shared__ int wsum[4];
    __shared__ int wsum2[4];
    const int t0 = tid * 16;
    int mv[16];
    {
      const int4* p = (const int4*)mask;
#pragma unroll
      for (int q = 0; q < 4; ++q) {
        const int4 v = p[tid * 4 + q];
        mv[q * 4 + 0] = v.x; mv[q * 4 + 1] = v.y;
        mv[q * 4 + 2] = v.z; mv[q * 4 + 3] = v.w;
      }
    }
    int f[16];
    int c = 0;
#pragma unroll
    for (int e = 0; e < 16; ++e) { f[e] = (mv[e] == 0); c += f[e]; }
    const int isc = wave_incl_scan(c, lane);
    if (lane == 63) wsum[wv] = isc;
    __syncthreads();
    if (tid == 0) {
      int accs = 0;
#pragma unroll
      for (int i = 0; i < 4; ++i) { int v = wsum[i]; wsum[i] = accs; accs += v; }
      sru[4096] = accs;
      ru[4096] = accs;
      counts[0] = accs;
    }
    __syncthreads();
    int ex = wsum[wv] + isc - c;
#pragma unroll
    for (int e = 0; e < 16; ++e) {
      sru[t0 + e] = ex;
      ru[t0 + e] = ex;
      ex += f[e];
    }
    __syncthreads();
    const int r = rptr[0];
    int g[16];
    int c2 = 0;
#pragma unroll
    for (int e = 0; e < 16; ++e) {
      const int t = t0 + e;
      const int s = t & 2047, tb = t & ~2047;
      const int lo = max(s - r, 0), hi = min(s + r, 2047);
      const int cnt = sru[tb + hi + 1] - sru[tb + lo];
      g[e] = (mv[e] != 0 && cnt > 0) ? 1 : 0;
      c2 += g[e];
    }
    const int isc2 = wave_incl_scan(c2, lane);
    if (lane == 63) wsum2[wv] = isc2;
    __syncthreads();
    if (tid == 0) {
      int accs = 0;
#pragma unroll
      for (int i = 0; i < 4; ++i) { int v = wsum2[i]; wsum2[i] = accs; accs += v; }
      counts[1] = accs;
    }
    __syncthreads();
    int ex2 = wsum2[wv] + isc2 - c2;
#pragma unroll
    for (int e = 0; e < 16; ++e) {
      const int t = t0 + e;
      pos2row[t] = g[e] ? ex2 : -1;
      if (g[e]) msk_idx[ex2] = t;
      ex2 += g[e];
    }
  }
}

// ---------------- GEMM C = A * Bt^T (A [M][Kstride], Bt [N][Kstride]) -----
// 64x128 tile, BK=32, 4 waves (2Mx2N; per-wave 32x64 output), 16x16x32
// MFMA. 3 LDS buffers (36KB -> 4 blocks/CU), counted vmcnt(3): wait tile t
// (3 insts/thread) while tile t+1 stays in flight; STAGE(t+2) issued right
// after the barrier, before COMPUTE(t). 1024 active blocks -> 4/CU
// co-resident staging streams (the measured lever).
// Split-K via blockIdx.z: K range [z*Kd, (z+1)*Kd), output to Cf0/Cf1.
template <int EPI>  // 0: f32 C to Cf{z}. 1: +bias, exact GELU, bf16 C.
__global__ __launch_bounds__(256, 4) void gemm_bt_kernel(
    const unsigned short* __restrict__ A, const unsigned short* __restrict__ Bt,
    float* __restrict__ Cf0, float* __restrict__ Cf1,
    unsigned short* __restrict__ Cb, const float* __restrict__ bias,
    const int* __restrict__ counts, int cidx, int N, int Kstride, int Kd) {
  const int Mlim = counts[cidx];
  const int bm = blockIdx.y * 64;
  if (bm >= Mlim) return;
  const int bn = blockIdx.x * 128;
  const int kofs = blockIdx.z * Kd;
  // per buffer (shorts): A 64x32 = 2048, B 128x32 = 4096
  constexpr int SBUF = 6144;
  __shared__ __align__(16) unsigned short L[3 * SBUF];
  const int tid = threadIdx.x;
  const int lane = tid & 63;
  const int wid = tid >> 6;  // 0..3
  const int wr = wid >> 1;   // 0..1 (M, 32 rows each)
  const int wc = wid & 1;    // 0..1 (N, 64 cols each)

  f32x4 acc[2][4];
#pragma unroll
  for (int m = 0; m < 2; ++m)
#pragma unroll
    for (int n = 0; n < 4; ++n) acc[m][n] = (f32x4){0.f, 0.f, 0.f, 0.f};

  // staging (linear LDS): per wave, A inst covers rows w*16..+15 (1KB),
  // B insts j=0,1 cover rows w*32+16j..+15. lane l -> row l>>2, slot l&3.
  const int l4 = lane >> 2;
  const int scol = (lane & 3) * 8;
  const unsigned short* gA0 =
      A + (size_t)(bm + wid * 16 + l4) * Kstride + kofs + scol;
  const unsigned short* gB0 =
      Bt + (size_t)(bn + wid * 32 + l4) * Kstride + kofs + scol;
  const unsigned short* gB1 = gB0 + (size_t)16 * Kstride;

  // compute-side read offsets (shorts)
  const int koff = (lane >> 4) * 8;
  const int aoff = (wr * 32 + (lane & 15)) * 32 + koff;
  const int boff = 2048 + (wc * 64 + (lane & 15)) * 32 + koff;

#define STAGE(buf, t)                                                         \
  {                                                                           \
    const int k0_ = (t) << 5;                                                 \
    unsigned short* la_ = L + (buf) * SBUF + wid * 512;                       \
    unsigned short* lb_ = L + (buf) * SBUF + 2048 + wid * 1024;               \
    GLD16(gA0 + k0_, la_);                                                    \
    GLD16(gB0 + k0_, lb_);                                                    \
    GLD16(gB1 + k0_, lb_ + 512);                                              \
  }

#define COMPUTE(buf)                                                          \
  {                                                                           \
    const unsigned short* bb_ = L + (buf) * SBUF;                             \
    bf16x8 af[2], bfr[4];                                                     \
    _Pragma("unroll") for (int m = 0; m < 2; ++m) af[m] =                     \
        LD8(bb_ + aoff + m * 512);                                            \
    _Pragma("unroll") for (int n = 0; n < 4; ++n) bfr[n] =                    \
        LD8(bb_ + boff + n * 512);                                            \
    _Pragma("unroll") for (int m = 0; m < 2; ++m)                             \
        _Pragma("unroll") for (int n = 0; n < 4; ++n) acc[m][n] =             \
            __builtin_amdgcn_mfma_f32_16x16x32_bf16(af[m], bfr[n],            \
                                                    acc[m][n], 0, 0, 0);      \
  }

  const int nt = Kd >> 5;  // 64
  STAGE(0, 0);
  STAGE(1, 1);
  int cb = 0, sb = 2;
#pragma unroll 1
  for (int t = 0; t < nt - 2; ++t) {
    asm volatile("s_waitcnt vmcnt(3)" ::: "memory");  // my tile-t loads landed
    __builtin_amdgcn_s_barrier();   // everyone's tile-t landed AND everyone
    __builtin_amdgcn_sched_barrier(0);  // finished reading buf sb (step t-1)
    STAGE(sb, t + 2);
    COMPUTE(cb);
    cb = (cb == 2) ? 0 : cb + 1;
    sb = (sb == 2) ? 0 : sb + 1;
  }
  asm volatile("s_waitcnt vmcnt(3)" ::: "memory");
  __builtin_amdgcn_s_barrier();
  __builtin_amdgcn_sched_barrier(0);
  COMPUTE(cb);
  cb = (cb == 2) ? 0 : cb + 1;
  asm volatile("s_waitcnt vmcnt(0)" ::: "memory");
  __builtin_amdgcn_s_barrier();
  __builtin_amdgcn_sched_barrier(0);
  COMPUTE(cb);
#undef STAGE
#undef COMPUTE

  float* __restrict__ Cf = (blockIdx.z == 0) ? Cf0 : Cf1;
  // C/D layout: col = lane&15, row = (lane>>4)*4 + i (m89/m91-verified)
  const int r0 = bm + wr * 32 + (lane >> 4) * 4;
  const int c0 = bn + wc * 64 + (lane & 15);
#pragma unroll
  for (int m = 0; m < 2; ++m) {
#pragma unroll
    for (int n = 0; n < 4; ++n) {
      const int col = c0 + n * 16;
#pragma unroll
      for (int ii = 0; ii < 4; ++ii) {
        const int row = r0 + m * 16 + ii;
        if (row >= Mlim) continue;
        const size_t off = (size_t)row * N + col;
        float v = acc[m][n][ii];
        if (EPI == 1) {
          v += bias[col];
          v = 0.5f * v * (1.0f + erff(v * 0.70710678118654752f));  // GELU
          Cb[off] = f2bf(v);
        } else {
          Cf[off] = v;
        }
      }
    }
  }
}

// ---------------- sliding-window neighbor sum + router weighting ----------
// Block = 256 threads over 2048 cols; per segment of 16 tokens keeps a
// running f32 window sum W: entering row added, leaving row subtracted.
__global__ __launch_bounds__(256) void window_kernel(
    const unsigned short* __restrict__ Act_c, const float* __restrict__ w,
    const int* __restrict__ ru, const int* __restrict__ pos2row,
    const int* __restrict__ rptr, unsigned short* __restrict__ G_c) {
  const int tid = threadIdx.x;
  const int b = blockIdx.y >> 7;        // batch
  const int seg = blockIdx.y & 127;     // 128 segments of 16 tokens
  const int s0 = seg * 16;
  const int tb = b * 2048;
  const int cbase = blockIdx.x * 2048 + tid * 8;
  const int kx = cbase >> 9;  // expert index (uniform per thread)
  const int r = rptr[0];

  float W[8] = {0.f, 0.f, 0.f, 0.f, 0.f, 0.f, 0.f, 0.f};
  // prologue: window of token s0 = unmasked rows in [s0-r, s0+r]
  for (int t = s0 - r; t <= s0 + r; ++t) {
    if (t < 0 || t > 2047) continue;
    const int j = ru[tb + t];
    if (ru[tb + t + 1] > j) {
      const short8 v = *(const short8*)(Act_c + (size_t)j * 4096 + cbase);
#pragma unroll
      for (int e = 0; e < 8; ++e) W[e] += bf2f((unsigned short)v[e]);
    }
  }
#pragma unroll 1
  for (int i = 0; i < 16; ++i) {
    const int t = s0 + i;
    const int a = tb + t;
    const int rowo = pos2row[a];
    if (rowo >= 0) {
      const float wv = w[(size_t)a * 8 + kx];
      short8 o8;
#pragma unroll
      for (int e = 0; e < 8; ++e) o8[e] = (short)f2bf(W[e] * wv);
      *(short8*)(G_c + (size_t)rowo * 4096 + cbase) = o8;
    }
    // advance window to token t+1: add t+1+r, remove t-r
    const int tin = t + r + 1;
    if (tin < 2048) {
      const int j = ru[tb + tin];
      if (ru[tb + tin + 1] > j) {
        const short8 v = *(const short8*)(Act_c + (size_t)j * 4096 + cbase);
#pragma unroll
        for (int e = 0; e < 8; ++e) W[e] += bf2f((unsigned short)v[e]);
      }
    }
    const int tout = t - r;
    if (tout >= 0) {
      const int j = ru[tb + tout];
      if (ru[tb + tout + 1] > j) {
        const short8 v = *(const short8*)(Act_c + (size_t)j * 4096 + cbase);
#pragma unroll
        for (int e = 0; e < 8; ++e) W[e] -= bf2f((unsigned short)v[e]);
      }
    }
  }
}

// ---------------- final: split-K combine, bias, mean, LN, blend -----------
__global__ void final_kernel(const float* __restrict__ h,
                             const int* __restrict__ pos2row,
                             const float* __restrict__ w,
                             const float* __restrict__ b2,
                             const float* __restrict__ p0,
                             const float* __restrict__ p1,
                             const int* __restrict__ ru,
                             const int* __restrict__ rptr,
                             float* __restrict__ out) {
  const int a = blockIdx.x;
  const int tid = threadIdx.x;
  const int lane = tid & 63, wid = tid >> 6;
  const size_t base = (size_t)a * 2048;
  const int d0 = tid * 8;
  const int row = pos2row[a];
  if (row < 0) {  // block-uniform: exact fp32 pass-through
    const float4 x0 = *(const float4*)(h + base + d0);
    const float4 x1 = *(const float4*)(h + base + d0 + 4);
    *(float4*)(out + base + d0) = x0;
    *(float4*)(out + base + d0 + 4) = x1;
    return;
  }
  const int s = a & 2047;
  const int tb = a & ~2047;
  const int r = rptr[0];
  const int lo = max(s - r, 0), hi = min(s + r, 2047);
  const int cnt = ru[tb + hi + 1] - ru[tb + lo];
  float wk[8];
#pragma unroll
  for (int k = 0; k < 8; ++k) wk[k] = w[(size_t)a * 8 + k];
  const float cntf = (float)cnt;
  const float icnt = 1.0f / cntf;
  float mval[8];
  float s1 = 0.f, s2 = 0.f;
#pragma unroll
  for (int j = 0; j < 8; ++j) {
    const int d = d0 + j;
    float wb2 = 0.f;
#pragma unroll
    for (int k = 0; k < 8; ++k) wb2 += wk[k] * b2[(size_t)k * 2048 + d];
    const size_t po = (size_t)row * 2048 + d;
    const float v = (p0[po] + p1[po] + cntf * wb2) * icnt;
    mval[j] = v;
    s1 += v;
    s2 += v * v;
  }
#pragma unroll
  for (int off = 32; off > 0; off >>= 1) {
    s1 += __shfl_down(s1, off);
    s2 += __shfl_down(s2, off);
  }
  __shared__ float red[8];
  if (lane == 0) {
    red[wid] = s1;
    red[4 + wid] = s2;
  }
  __syncthreads();
  const float S1 = red[0] + red[1] + red[2] + red[3];
  const float S2 = red[4] + red[5] + red[6] + red[7];
  const float mu = S1 * (1.0f / 2048.0f);
  const float var = S2 * (1.0f / 2048.0f) - mu * mu;
  const float rin = rsqrtf(var + EPS);
#pragma unroll
  for (int j = 0; j < 8; ++j) {
    const int d = d0 + j;
    out[base + d] = h[base + d] + ALPHA * ((mval[j] - mu) * rin);
  }
}

// ---------------- launch ----------------
extern "C" void kernel_launch(void* const* d_in, const int* in_sizes, int n_in,
                              void* d_out, int out_size, void* d_ws,
                              size_t ws_size, hipStream_t stream) {
  const float* h = (const float*)d_in[0];
  const int* mask = (const int*)d_in[1];
  const float* Wr = (const float*)d_in[2];
  const float* br = (const float*)d_in[3];
  const float* W1 = (const float*)d_in[4];
  const float* b1 = (const float*)d_in[5];
  const float* W2 = (const float*)d_in[6];
  const float* b2 = (const float*)d_in[7];
  const int* rptr = (const int*)d_in[8];
  float* out = (float*)d_out;

  char* ws = (char*)d_ws;
  // layout (bytes):
  //   hbc  [4096*2048] bf16 @ 0          (16 MiB)  compact unmasked h
  //   B1t  [4096*2048] bf16 @ 16777216   (16 MiB)  W1^T stacked [kf][d]
  //     (hbc+B1t region is dead after GEMM1 -> reused as p1 f32 32 MiB)
  //   B2t  [2048*4096] bf16 @ 33554432   (16 MiB)  W2^T stacked [d][kf]
  //   Act_c[4096*4096] bf16 @ 50331648   (32 MiB)  (dead after window ->
  //                                                 reused as p0 f32 32 MiB)
  //   G_c  [4096*4096] bf16 @ 83886080   (32 MiB)
  //   w    [4096*8]    f32  @ 117440512  (128 KiB)
  //   ints: ru[4097+], msk_idx[4096], pos2row[4096], counts[2]
  unsigned short* hbc = (unsigned short*)(ws + 0);
  unsigned short* B1t = (unsigned short*)(ws + 16777216);
  unsigned short* B2t = (unsigned short*)(ws + 33554432);
  unsigned short* Act_c = (unsigned short*)(ws + 50331648);
  unsigned short* G_c = (unsigned short*)(ws + 83886080);
  float* p0 = (float*)(ws + 50331648);  // alias Act_c (dead after window)
  float* p1 = (float*)(ws + 0);         // alias hbc+B1t (dead after GEMM1)
  float* wbuf = (float*)(ws + 117440512);
  int* ru = (int*)(ws + 117571584);
  int* msk_idx = ru + 4100;
  int* pos2row = msk_idx + 4096;
  int* counts = pos2row + 4096;

  // prep: tpack (16384) + packrouter (4096) + scan (1)
  prep_kernel<<<20481, 256, 0, stream>>>(h, mask, Wr, br, W1, W2, rptr, wbuf,
                                         hbc, B1t, B2t, ru, msk_idx, pos2row,
                                         counts);
  // GEMM1: Act_c = gelu(hbc * B1t^T + b1)  [Nu x 4096], K=2048
  gemm_bt_kernel<1><<<dim3(32, 64, 1), 256, 0, stream>>>(
      hbc, B1t, nullptr, nullptr, Act_c, b1, counts, 0, 4096, 2048, 2048);
  // G_c = w * sliding-window-sum(Act_c)  [Nm x 4096]
  window_kernel<<<dim3(2, 256), 256, 0, stream>>>(Act_c, wbuf, ru, pos2row,
                                                  rptr, G_c);
  // GEMM2: p{0,1} = G_c * B2t^T partials  [Nm x 2048], K=4096 split 2x2048
  gemm_bt_kernel<0><<<dim3(16, 64, 2), 256, 0, stream>>>(
      G_c, B2t, p0, p1, nullptr, nullptr, counts, 1, 2048, 4096, 2048);
  final_kernel<<<4096, 256, 0, stream>>>(h, pos2row, wbuf, b2, p0, p1, ru,
                                         rptr, out);
}

// Round 9
// 332.485 us; speedup vs baseline: 1.0182x; 1.0182x over previous
//
#include <hip/hip_runtime.h>
#include <hip/hip_bf16.h>
#include <math.h>

// ALALLaDA router blend, factored + row-compacted form:
//   prep: scan + router softmax + bf16 compact pack + W1/W2 transpose-pack
//   Act_c[i, kf] = gelu(h_unm[i,:]·W1 + b1)               (GEMM1, M=Nu)
//   G_c[i, kf]   = w[a]*slidingwin(Act_c)                 (window kernel)
//   num_c[i,:]   = G_c[i,:]·W2s  (split-K=2 partials)     (GEMM2, M=Nm)
//   out = h + 0.08*LN((p0+p1+cnt*w·b2)/cnt) at active masked positions.
// GEMM: m201-style 8-phase schedule on 128x256 tiles, 8 waves (2Mx4N),
// BK=64, 4 phases/K-tile {ds_read || global_load_lds -> barrier ->
// lgkmcnt(0) -> setprio(1) 8xMFMA setprio(0) -> barrier}, ONE counted
// vmcnt(6) per K-tile (never 0 mid-loop), 3 LDS buffers (144KB, stage
// t+2 during t), T2 swizzle (16B slot ^= row&7; linear LDS dest +
// inverse-permuted global source + swizzled ds_read, rule #21), T5
// setprio. Regime gate (m228d/m230): T2/T5 pay ONLY inside this
// fine-interleaved structure — 2-phase variants all plateaued 75-100us.

#define ALPHA 0.08f
#define EPS 1e-5f

typedef __attribute__((ext_vector_type(8))) __bf16 bf16x8;
typedef __attribute__((ext_vector_type(8))) short short8;
typedef __attribute__((ext_vector_type(4))) float f32x4;

__device__ __forceinline__ unsigned short f2bf(float f) {
  unsigned u = __float_as_uint(f);
  u += 0x7fffu + ((u >> 16) & 1u);
  return (unsigned short)(u >> 16);
}
__device__ __forceinline__ float bf2f(unsigned short b) {
  return __uint_as_float(((unsigned)b) << 16);
}

#define GLD16(gptr, lptr)                                                     \
  __builtin_amdgcn_global_load_lds(                                           \
      (const __attribute__((address_space(1))) void*)(gptr),                  \
      (__attribute__((address_space(3))) void*)(lptr), 16, 0, 0)

#define LD8(p) __builtin_bit_cast(bf16x8, *(const short8*)(p))

__device__ __forceinline__ int wave_incl_scan(int v, int lane) {
#pragma unroll
  for (int off = 1; off < 64; off <<= 1) {
    int t = __shfl_up(v, off);
    if (lane >= off) v += t;
  }
  return v;
}

// ---------------- prep: tpack (blocks 0..16383) + packrouter (16384..20479)
//                  + scan (block 20480), 256 threads each ----------------
__global__ __launch_bounds__(256) void prep_kernel(
    const float* __restrict__ h, const int* __restrict__ mask,
    const float* __restrict__ Wr, const float* __restrict__ br,
    const float* __restrict__ W1, const float* __restrict__ W2,
    const int* __restrict__ rptr, float* __restrict__ w,
    unsigned short* __restrict__ hbc, unsigned short* __restrict__ B1t,
    unsigned short* __restrict__ B2t, int* __restrict__ ru,
    int* __restrict__ msk_idx, int* __restrict__ pos2row,
    int* __restrict__ counts) {
  const int bid = blockIdx.x;
  const int tid = threadIdx.x;
  const int lane = tid & 63, wv = tid >> 6;

  if (bid < 16384) {  // ---- transpose-pack W1 / W2 ----
    __shared__ float tile[32][33];
    int id = bid;
    const float* src;
    unsigned short* dst;
    int C, c0, r0;
    size_t dstStride;
    if (id < 8192) {  // W1 [k][2048][512] -> B1t[(k*512+f)*2048 + d]
      const int k = id >> 10, rem = id & 1023;
      src = W1 + (size_t)k * 2048 * 512;
      dst = B1t + (size_t)k * 512 * 2048;
      C = 512; dstStride = 2048;
      c0 = (rem >> 6) * 32; r0 = (rem & 63) * 32;
    } else {          // W2 [k][512][2048] -> B2t[d*4096 + k*512 + f]
      id -= 8192;
      const int k = id >> 10, rem = id & 1023;
      src = W2 + (size_t)k * 512 * 2048;
      dst = B2t + (size_t)k * 512;
      C = 2048; dstStride = 4096;
      c0 = (rem >> 4) * 32; r0 = (rem & 15) * 32;
    }
    const int tx = tid & 31, ty = tid >> 5;
#pragma unroll
    for (int i = 0; i < 4; ++i)
      tile[ty + 8 * i][tx] = src[(size_t)(r0 + ty + 8 * i) * C + (c0 + tx)];
    __syncthreads();
#pragma unroll
    for (int i = 0; i < 4; ++i) {
      const int c = c0 + ty + 8 * i;
      dst[(size_t)c * dstStride + (size_t)(r0 + tx)] =
          f2bf(tile[tx][ty + 8 * i]);
    }
    return;
  }

  if (bid < 20480) {  // ---- router softmax + compact bf16 pack of h ----
    const int a = bid - 16384;
    const size_t base = (size_t)a * 2048;
    const int d0 = tid * 8;
    float hv[8];
    *(float4*)(hv) = *(const float4*)(h + base + d0);
    *(float4*)(hv + 4) = *(const float4*)(h + base + d0 + 4);
    float acc[8];
#pragma unroll
    for (int k = 0; k < 8; ++k) {
      float wvv[8];
      *(float4*)(wvv) = *(const float4*)(Wr + (size_t)k * 2048 + d0);
      *(float4*)(wvv + 4) = *(const float4*)(Wr + (size_t)k * 2048 + d0 + 4);
      float s = 0.f;
#pragma unroll
      for (int j = 0; j < 8; ++j) s += hv[j] * wvv[j];
      acc[k] = s;
    }
    // my compact row index: zeros in mask[0..a)  (self-computed, no dep)
    int c0n = 0;
    {
      const int4* m4p = (const int4*)mask;
#pragma unroll
      for (int q = 0; q < 4; ++q) {
        const int4 v = m4p[tid * 4 + q];
        const int b0 = tid * 16 + q * 4;
        c0n += (v.x == 0 && b0 + 0 < a);
        c0n += (v.y == 0 && b0 + 1 < a);
        c0n += (v.z == 0 && b0 + 2 < a);
        c0n += (v.w == 0 && b0 + 3 < a);
      }
    }
#pragma unroll
    for (int off = 32; off > 0; off >>= 1) {
      c0n += __shfl_down(c0n, off);
#pragma unroll
      for (int k = 0; k < 8; ++k) acc[k] += __shfl_down(acc[k], off);
    }
    __shared__ float red[4][8];
    __shared__ float logits[8];
    __shared__ int rucnt[4];
    __shared__ int rubc;
    if (lane == 0) {
#pragma unroll
      for (int k = 0; k < 8; ++k) red[wv][k] = acc[k];
      rucnt[wv] = c0n;
    }
    __syncthreads();
    if (tid < 8)
      logits[tid] =
          red[0][tid] + red[1][tid] + red[2][tid] + red[3][tid] + br[tid];
    if (tid == 0) rubc = rucnt[0] + rucnt[1] + rucnt[2] + rucnt[3];
    __syncthreads();
    if (tid == 0) {
      float mx = logits[0];
#pragma unroll
      for (int k = 1; k < 8; ++k) mx = fmaxf(mx, logits[k]);
      float e[8], se = 0.f;
#pragma unroll
      for (int k = 0; k < 8; ++k) {
        e[k] = expf(logits[k] - mx);
        se += e[k];
      }
      const float is = 1.f / se;
#pragma unroll
      for (int k = 0; k < 8; ++k) w[(size_t)a * 8 + k] = e[k] * is;
    }
    if (mask[a] == 0) {
      const int i = rubc;
      short8 o;
#pragma unroll
      for (int j = 0; j < 8; ++j) o[j] = (short)f2bf(hv[j]);
      *(short8*)(hbc + (size_t)i * 2048 + d0) = o;
    }
    return;
  }

  // ---- scan block (bid == 20480): ru, msk_idx, pos2row, counts ----
  {
    __shared__ int sru[4097];
    __shared__ int wsum[4];
    __shared__ int wsum2[4];
    const int t0 = tid * 16;
    int mv[16];
    {
      const int4* p = (const int4*)mask;
#pragma unroll
      for (int q = 0; q < 4; ++q) {
        const int4 v = p[tid * 4 + q];
        mv[q * 4 + 0] = v.x; mv[q * 4 + 1] = v.y;
        mv[q * 4 + 2] = v.z; mv[q * 4 + 3] = v.w;
      }
    }
    int f[16];
    int c = 0;
#pragma unroll
    for (int e = 0; e < 16; ++e) { f[e] = (mv[e] == 0); c += f[e]; }
    const int isc = wave_incl_scan(c, lane);
    if (lane == 63) wsum[wv] = isc;
    __syncthreads();
    if (tid == 0) {
      int accs = 0;
#pragma unroll
      for (int i = 0; i < 4; ++i) { int v = wsum[i]; wsum[i] = accs; accs += v; }
      sru[4096] = accs;
      ru[4096] = accs;
      counts[0] = accs;
    }
    __syncthreads();
    int ex = wsum[wv] + isc - c;
#pragma unroll
    for (int e = 0; e < 16; ++e) {
      sru[t0 + e] = ex;
      ru[t0 + e] = ex;
      ex += f[e];
    }
    __syncthreads();
    const int r = rptr[0];
    int g[16];
    int c2 = 0;
#pragma unroll
    for (int e = 0; e < 16; ++e) {
      const int t = t0 + e;
      const int s = t & 2047, tb = t & ~2047;
      const int lo = max(s - r, 0), hi = min(s + r, 2047);
      const int cnt = sru[tb + hi + 1] - sru[tb + lo];
      g[e] = (mv[e] != 0 && cnt > 0) ? 1 : 0;
      c2 += g[e];
    }
    const int isc2 = wave_incl_scan(c2, lane);
    if (lane == 63) wsum2[wv] = isc2;
    __syncthreads();
    if (tid == 0) {
      int accs = 0;
#pragma unroll
      for (int i = 0; i < 4; ++i) { int v = wsum2[i]; wsum2[i] = accs; accs += v; }
      counts[1] = accs;
    }
    __syncthreads();
    int ex2 = wsum2[wv] + isc2 - c2;
#pragma unroll
    for (int e = 0; e < 16; ++e) {
      const int t = t0 + e;
      pos2row[t] = g[e] ? ex2 : -1;
      if (g[e]) msk_idx[ex2] = t;
      ex2 += g[e];
    }
  }
}

// ---------------- 8-phase GEMM C = A * Bt^T --------------------------------
// A [M][Kstride], Bt [N][Kstride] bf16 row-major. 128x256 tile, BK=64,
// 8 waves (2Mx4N; 64x64/wave), 16x16x32 MFMA. 3 LDS buffers (144KB ->
// 1 block/CU, 8 waves). Per K-tile: 4 phases, each {4-8 ds_read_b128 ||
// one 2-inst stage unit -> barrier -> lgkmcnt(0) -> sched_barrier ->
// setprio(1) 8 MFMA setprio(0) -> barrier}; vmcnt(6) ONCE per tile (ph3).
// Stage tile t+2 into buf[(t+2)%3] during tile t.
// T2 swizzle: LDS 16B-slot s of row r holds global granule s^(r&7);
// staging pre-permutes per-lane global col; ds_read XORs the slot.
// Split-K via blockIdx.z: K range [z*Kd, (z+1)*Kd) -> Cf0/Cf1.
template <int EPI>  // 0: f32 C to Cf{z}. 1: +bias, exact GELU, bf16 C.
__global__ __launch_bounds__(512, 2) void gemm8p_kernel(
    const unsigned short* __restrict__ A, const unsigned short* __restrict__ Bt,
    float* __restrict__ Cf0, float* __restrict__ Cf1,
    unsigned short* __restrict__ Cb, const float* __restrict__ bias,
    const int* __restrict__ counts, int cidx, int N, int Kstride, int Kd) {
  const int Mlim = counts[cidx];
  const int bm = blockIdx.y * 128;
  if (bm >= Mlim) return;
  const int bn = blockIdx.x * 256;
  const int kofs = blockIdx.z * Kd;
  constexpr int SA = 8192;      // A region shorts (128x64)
  constexpr int SBUF = 24576;   // + B region (256x64)
  __shared__ __align__(16) unsigned short L[3 * SBUF];  // 144 KB
  const int tid = threadIdx.x;  // 0..511
  const int lane = tid & 63;
  const int wid = tid >> 6;     // 0..7
  const int wr = wid >> 2;      // 0..1 (M half: 64 rows)
  const int wc = wid & 3;       // 0..3 (N quarter: 64 cols)

  f32x4 acc[4][4];
#pragma unroll
  for (int m = 0; m < 4; ++m)
#pragma unroll
    for (int n = 0; n < 4; ++n) acc[m][n] = (f32x4){0.f, 0.f, 0.f, 0.f};

  // staging addresses: thread t -> row t>>3 (+64 per inst), slot t&7;
  // global source granule pre-permuted: (t&7) ^ ((t>>3)&7).
  const int trow = tid >> 3;                       // 0..63
  const int scol = ((tid & 7) ^ (trow & 7)) * 8;   // shorts
  const unsigned short* gA =
      A + (size_t)(bm + trow) * Kstride + kofs + scol;
  const unsigned short* gB =
      Bt + (size_t)(bn + trow) * Kstride + kofs + scol;
  unsigned short* const ld0 = (unsigned short*)L + tid * 8;

  // compute-side swizzled read offsets (shorts); row&7 == lane&7.
  const int x7 = lane & 7;
  const int t16 = lane >> 4;                 // 0..3
  const int s0 = (t16 ^ x7) * 8;             // kk=0 granule
  const int s1 = ((4 + t16) ^ x7) * 8;       // kk=1 granule
  const int arow = (wr * 64 + (lane & 15)) * 64;
  const int brow = SA + (wc * 64 + (lane & 15)) * 64;

  bf16x8 afr[2][2], b0f[2][2], b1f[2][2];

#define STAGE_A(buf, k0)                                                      \
  {                                                                           \
    unsigned short* d_ = ld0 + (buf) * SBUF;                                  \
    GLD16(gA + (k0), d_);                                                     \
    GLD16(gA + (size_t)64 * Kstride + (k0), d_ + 4096);                       \
  }
#define STAGE_B0(buf, k0)                                                     \
  {                                                                           \
    unsigned short* d_ = ld0 + (buf) * SBUF + SA;                             \
    GLD16(gB + (k0), d_);                                                     \
    GLD16(gB + (size_t)64 * Kstride + (k0), d_ + 4096);                       \
  }
#define STAGE_B1(buf, k0)                                                     \
  {                                                                           \
    unsigned short* d_ = ld0 + (buf) * SBUF + SA + 8192;                      \
    GLD16(gB + (size_t)128 * Kstride + (k0), d_);                             \
    GLD16(gB + (size_t)192 * Kstride + (k0), d_ + 4096);                      \
  }
#define RD_A(cb_, half)                                                       \
  _Pragma("unroll") for (int m = 0; m < 2; ++m) {                             \
    afr[m][0] = LD8((cb_) + arow + ((half) * 2 + m) * 1024 + s0);             \
    afr[m][1] = LD8((cb_) + arow + ((half) * 2 + m) * 1024 + s1);             \
  }
#define RD_B(cb_, half, bf)                                                   \
  _Pragma("unroll") for (int n = 0; n < 2; ++n) {                             \
    bf[n][0] = LD8((cb_) + brow + ((half) * 2 + n) * 1024 + s0);              \
    bf[n][1] = LD8((cb_) + brow + ((half) * 2 + n) * 1024 + s1);              \
  }
#define QMFMA(mb, nb, bf)                                                     \
  _Pragma("unroll") for (int m = 0; m < 2; ++m)                               \
      _Pragma("unroll") for (int n = 0; n < 2; ++n) {                         \
    acc[(mb) + m][(nb) + n] = __builtin_amdgcn_mfma_f32_16x16x32_bf16(        \
        afr[m][0], bf[n][0], acc[(mb) + m][(nb) + n], 0, 0, 0);               \
    acc[(mb) + m][(nb) + n] = __builtin_amdgcn_mfma_f32_16x16x32_bf16(        \
        afr[m][1], bf[n][1], acc[(mb) + m][(nb) + n], 0, 0, 0);               \
  }
#define PHASE_SYNC                                                            \
  __builtin_amdgcn_s_barrier();                                               \
  asm volatile("s_waitcnt lgkmcnt(0)" ::: "memory");                          \
  __builtin_amdgcn_sched_barrier(0);

  const int nt = Kd >> 6;  // 32
  STAGE_A(0, 0); STAGE_B0(0, 0); STAGE_B1(0, 0);
  STAGE_A(1, 64); STAGE_B0(1, 64); STAGE_B1(1, 64);
  asm volatile("s_waitcnt vmcnt(6)" ::: "memory");  // tile 0 landed
  __builtin_amdgcn_s_barrier();

#pragma unroll 1
  for (int t = 0; t < nt; ++t) {
    const int cbuf = t % 3;
    const int sbuf = (t + 2) % 3;
    const unsigned short* cb_ = (const unsigned short*)L + cbuf * SBUF;
    const bool st = (t + 2) < nt;
    const int k2 = (t + 2) << 6;
    // ---- phase 0: read A-half0 + B-half0; stage A unit; MFMA q(0,0) ----
    RD_A(cb_, 0);
    RD_B(cb_, 0, b0f);
    if (st) STAGE_A(sbuf, k2);
    PHASE_SYNC;
    __builtin_amdgcn_s_setprio(1);
    QMFMA(0, 0, b0f);
    __builtin_amdgcn_s_setprio(0);
    __builtin_amdgcn_s_barrier();
    // ---- phase 1: read B-half1; stage B0 unit; MFMA q(0,1) ----
    RD_B(cb_, 1, b1f);
    if (st) STAGE_B0(sbuf, k2);
    PHASE_SYNC;
    __builtin_amdgcn_s_setprio(1);
    QMFMA(0, 2, b1f);
    __builtin_amdgcn_s_setprio(0);
    __builtin_amdgcn_s_barrier();
    // ---- phase 2: read A-half1; stage B1 unit; MFMA q(1,1) ----
    RD_A(cb_, 1);
    if (st) STAGE_B1(sbuf, k2);
    PHASE_SYNC;
    __builtin_amdgcn_s_setprio(1);
    QMFMA(2, 2, b1f);
    __builtin_amdgcn_s_setprio(0);
    __builtin_amdgcn_s_barrier();
    // ---- phase 3: counted vmcnt (next tile ready); MFMA q(1,0) ----
    if (t < nt - 2) {
      asm volatile("s_waitcnt vmcnt(6)" ::: "memory");
    } else {
      asm volatile("s_waitcnt vmcnt(0)" ::: "memory");
    }
    __builtin_amdgcn_s_barrier();
    __builtin_amdgcn_sched_barrier(0);
    __builtin_amdgcn_s_setprio(1);
    QMFMA(2, 0, b0f);
    __builtin_amdgcn_s_setprio(0);
    __builtin_amdgcn_s_barrier();
  }
#undef STAGE_A
#undef STAGE_B0
#undef STAGE_B1
#undef RD_A
#undef RD_B
#undef QMFMA
#undef PHASE_SYNC

  float* __restrict__ Cf = (blockIdx.z == 0) ? Cf0 : Cf1;
  // C/D layout: col = lane&15, row = (lane>>4)*4 + i (m89/m91-verified)
  const int r0 = bm + wr * 64 + (lane >> 4) * 4;
  const int c0 = bn + wc * 64 + (lane & 15);
#pragma unroll
  for (int m = 0; m < 4; ++m) {
#pragma unroll
    for (int n = 0; n < 4; ++n) {
      const int col = c0 + n * 16;
#pragma unroll
      for (int ii = 0; ii < 4; ++ii) {
        const int row = r0 + m * 16 + ii;
        if (row >= Mlim) continue;
        const size_t off = (size_t)row * N + col;
        float v = acc[m][n][ii];
        if (EPI == 1) {
          v += bias[col];
          v = 0.5f * v * (1.0f + erff(v * 0.70710678118654752f));  // GELU
          Cb[off] = f2bf(v);
        } else {
          Cf[off] = v;
        }
      }
    }
  }
}

// ---------------- sliding-window neighbor sum + router weighting ----------
__global__ __launch_bounds__(256) void window_kernel(
    const unsigned short* __restrict__ Act_c, const float* __restrict__ w,
    const int* __restrict__ ru, const int* __restrict__ pos2row,
    const int* __restrict__ rptr, unsigned short* __restrict__ G_c) {
  const int tid = threadIdx.x;
  const int b = blockIdx.y >> 7;        // batch
  const int seg = blockIdx.y & 127;     // 128 segments of 16 tokens
  const int s0 = seg * 16;
  const int tb = b * 2048;
  const int cbase = blockIdx.x * 2048 + tid * 8;
  const int kx = cbase >> 9;  // expert index (uniform per thread)
  const int r = rptr[0];

  float W[8] = {0.f, 0.f, 0.f, 0.f, 0.f, 0.f, 0.f, 0.f};
  for (int t = s0 - r; t <= s0 + r; ++t) {
    if (t < 0 || t > 2047) continue;
    const int j = ru[tb + t];
    if (ru[tb + t + 1] > j) {
      const short8 v = *(const short8*)(Act_c + (size_t)j * 4096 + cbase);
#pragma unroll
      for (int e = 0; e < 8; ++e) W[e] += bf2f((unsigned short)v[e]);
    }
  }
#pragma unroll 1
  for (int i = 0; i < 16; ++i) {
    const int t = s0 + i;
    const int a = tb + t;
    const int rowo = pos2row[a];
    if (rowo >= 0) {
      const float wv = w[(size_t)a * 8 + kx];
      short8 o8;
#pragma unroll
      for (int e = 0; e < 8; ++e) o8[e] = (short)f2bf(W[e] * wv);
      *(short8*)(G_c + (size_t)rowo * 4096 + cbase) = o8;
    }
    const int tin = t + r + 1;
    if (tin < 2048) {
      const int j = ru[tb + tin];
      if (ru[tb + tin + 1] > j) {
        const short8 v = *(const short8*)(Act_c + (size_t)j * 4096 + cbase);
#pragma unroll
        for (int e = 0; e < 8; ++e) W[e] += bf2f((unsigned short)v[e]);
      }
    }
    const int tout = t - r;
    if (tout >= 0) {
      const int j = ru[tb + tout];
      if (ru[tb + tout + 1] > j) {
        const short8 v = *(const short8*)(Act_c + (size_t)j * 4096 + cbase);
#pragma unroll
        for (int e = 0; e < 8; ++e) W[e] -= bf2f((unsigned short)v[e]);
      }
    }
  }
}

// ---------------- final: split-K combine, bias, mean, LN, blend -----------
__global__ void final_kernel(const float* __restrict__ h,
                             const int* __restrict__ pos2row,
                             const float* __restrict__ w,
                             const float* __restrict__ b2,
                             const float* __restrict__ p0,
                             const float* __restrict__ p1,
                             const int* __restrict__ ru,
                             const int* __restrict__ rptr,
                             float* __restrict__ out) {
  const int a = blockIdx.x;
  const int tid = threadIdx.x;
  const int lane = tid & 63, wid = tid >> 6;
  const size_t base = (size_t)a * 2048;
  const int d0 = tid * 8;
  const int row = pos2row[a];
  if (row < 0) {  // block-uniform: exact fp32 pass-through
    const float4 x0 = *(const float4*)(h + base + d0);
    const float4 x1 = *(const float4*)(h + base + d0 + 4);
    *(float4*)(out + base + d0) = x0;
    *(float4*)(out + base + d0 + 4) = x1;
    return;
  }
  const int s = a & 2047;
  const int tb = a & ~2047;
  const int r = rptr[0];
  const int lo = max(s - r, 0), hi = min(s + r, 2047);
  const int cnt = ru[tb + hi + 1] - ru[tb + lo];
  float wk[8];
#pragma unroll
  for (int k = 0; k < 8; ++k) wk[k] = w[(size_t)a * 8 + k];
  const float cntf = (float)cnt;
  const float icnt = 1.0f / cntf;
  float mval[8];
  float s1 = 0.f, s2 = 0.f;
#pragma unroll
  for (int j = 0; j < 8; ++j) {
    const int d = d0 + j;
    float wb2 = 0.f;
#pragma unroll
    for (int k = 0; k < 8; ++k) wb2 += wk[k] * b2[(size_t)k * 2048 + d];
    const size_t po = (size_t)row * 2048 + d;
    const float v = (p0[po] + p1[po] + cntf * wb2) * icnt;
    mval[j] = v;
    s1 += v;
    s2 += v * v;
  }
#pragma unroll
  for (int off = 32; off > 0; off >>= 1) {
    s1 += __shfl_down(s1, off);
    s2 += __shfl_down(s2, off);
  }
  __shared__ float red[8];
  if (lane == 0) {
    red[wid] = s1;
    red[4 + wid] = s2;
  }
  __syncthreads();
  const float S1 = red[0] + red[1] + red[2] + red[3];
  const float S2 = red[4] + red[5] + red[6] + red[7];
  const float mu = S1 * (1.0f / 2048.0f);
  const float var = S2 * (1.0f / 2048.0f) - mu * mu;
  const float rin = rsqrtf(var + EPS);
#pragma unroll
  for (int j = 0; j < 8; ++j) {
    const int d = d0 + j;
    out[base + d] = h[base + d] + ALPHA * ((mval[j] - mu) * rin);
  }
}

// ---------------- launch ----------------
extern "C" void kernel_launch(void* const* d_in, const int* in_sizes, int n_in,
                              void* d_out, int out_size, void* d_ws,
                              size_t ws_size, hipStream_t stream) {
  const float* h = (const float*)d_in[0];
  const int* mask = (const int*)d_in[1];
  const float* Wr = (const float*)d_in[2];
  const float* br = (const float*)d_in[3];
  const float* W1 = (const float*)d_in[4];
  const float* b1 = (const float*)d_in[5];
  const float* W2 = (const float*)d_in[6];
  const float* b2 = (const float*)d_in[7];
  const int* rptr = (const int*)d_in[8];
  float* out = (float*)d_out;

  char* ws = (char*)d_ws;
  // layout (bytes):
  //   hbc  [4096*2048] bf16 @ 0          (16 MiB)  compact unmasked h
  //   B1t  [4096*2048] bf16 @ 16777216   (16 MiB)  W1^T stacked [kf][d]
  //     (hbc+B1t region is dead after GEMM1 -> reused as p1 f32 32 MiB)
  //   B2t  [2048*4096] bf16 @ 33554432   (16 MiB)  W2^T stacked [d][kf]
  //   Act_c[4096*4096] bf16 @ 50331648   (32 MiB)  (dead after window ->
  //                                                 reused as p0 f32 32 MiB)
  //   G_c  [4096*4096] bf16 @ 83886080   (32 MiB)
  //   w    [4096*8]    f32  @ 117440512  (128 KiB)
  //   ints: ru[4097+], msk_idx[4096], pos2row[4096], counts[2]
  unsigned short* hbc = (unsigned short*)(ws + 0);
  unsigned short* B1t = (unsigned short*)(ws + 16777216);
  unsigned short* B2t = (unsigned short*)(ws + 33554432);
  unsigned short* Act_c = (unsigned short*)(ws + 50331648);
  unsigned short* G_c = (unsigned short*)(ws + 83886080);
  float* p0 = (float*)(ws + 50331648);  // alias Act_c (dead after window)
  float* p1 = (float*)(ws + 0);         // alias hbc+B1t (dead after GEMM1)
  float* wbuf = (float*)(ws + 117440512);
  int* ru = (int*)(ws + 117571584);
  int* msk_idx = ru + 4100;
  int* pos2row = msk_idx + 4096;
  int* counts = pos2row + 4096;

  // prep: tpack (16384) + packrouter (4096) + scan (1)
  prep_kernel<<<20481, 256, 0, stream>>>(h, mask, Wr, br, W1, W2, rptr, wbuf,
                                         hbc, B1t, B2t, ru, msk_idx, pos2row,
                                         counts);
  // GEMM1: Act_c = gelu(hbc * B1t^T + b1)  [Nu x 4096], K=2048
  gemm8p_kernel<1><<<dim3(16, 32, 1), 512, 0, stream>>>(
      hbc, B1t, nullptr, nullptr, Act_c, b1, counts, 0, 4096, 2048, 2048);
  // G_c = w * sliding-window-sum(Act_c)  [Nm x 4096]
  window_kernel<<<dim3(2, 256), 256, 0, stream>>>(Act_c, wbuf, ru, pos2row,
                                                  rptr, G_c);
  // GEMM2: p{0,1} = G_c * B2t^T partials  [Nm x 2048], K=4096 split 2x2048
  gemm8p_kernel<0><<<dim3(8, 32, 2), 512, 0, stream>>>(
      G_c, B2t, p0, p1, nullptr, nullptr, counts, 1, 2048, 4096, 2048);
  final_kernel<<<4096, 256, 0, stream>>>(h, pos2row, wbuf, b2, p0, p1, ru,
                                         rptr, out);
}